// Round 2
// baseline (1843.864 us; speedup 1.0000x reference)
//
#include <hip/hip_runtime.h>

typedef unsigned short u16;

#define HID 64
#define MOLD 9
#define SCAN_B 512

__device__ __forceinline__ float bf2f(u16 u) {
    return __uint_as_float(((unsigned)u) << 16);
}
__device__ __forceinline__ u16 f2bf(float f) {
    unsigned x = __float_as_uint(f);
    unsigned r = (x + 0x7FFFu + ((x >> 16) & 1u)) >> 16;  // round-nearest-even
    return (u16)r;
}

// ---- dtype probe: bf16 x~N(0,1) never exceeds |1000|; f32-bits-as-bf16 does ----
__global__ void k_detect(const u16* __restrict__ p, int n, int* __restrict__ flag) {
    bool bad = false;
    for (int i = threadIdx.x; i < n; i += 256) {
        float v = bf2f(p[i]);
        if (!(v == v) || fabsf(v) > 1000.f) bad = true;
    }
    if (bad) atomicOr(flag, 1);
}

__device__ __forceinline__ void cvt_seg(const void* src, u16* dst, int n, int mode) {
    if (mode) {
        const float* s = (const float*)src;
        for (int i = threadIdx.x; i < n; i += 256) dst[i] = f2bf(s[i]);
    } else {
        const u16* s = (const u16*)src;
        for (int i = threadIdx.x; i < n; i += 256) dst[i] = s[i];
    }
}

// stage all 8 weight tensors as bf16 bits into wbf (offsets hardcoded)
__global__ void k_cvt_w(const void* W1, const void* b1, const void* W2, const void* b2,
                        const void* W3, const void* b3, const void* Wl, const void* bl,
                        const int* __restrict__ flag, u16* __restrict__ wbf) {
    int mode = *flag;
    cvt_seg(W1, wbf + 0,     MOLD * HID, mode);   // 576
    cvt_seg(b1, wbf + 576,   HID, mode);          // 64
    cvt_seg(W2, wbf + 640,   HID * HID, mode);    // 4096
    cvt_seg(b2, wbf + 4736,  HID, mode);
    cvt_seg(W3, wbf + 4800,  HID * HID, mode);
    cvt_seg(b3, wbf + 8896,  HID, mode);
    cvt_seg(Wl, wbf + 8960,  2 * HID * HID, mode); // 8192
    cvt_seg(bl, wbf + 17152, HID, mode);
}

__global__ void k_cvt_x(const void* __restrict__ src, u16* __restrict__ dst, int n,
                        const int* __restrict__ flag) {
    int mode = *flag;
    int i = blockIdx.x * 256 + threadIdx.x;
    if (i >= n) return;
    dst[i] = mode ? f2bf(((const float*)src)[i]) : ((const u16*)src)[i];
}

// ---- degree count over real edges ----
__global__ void k_count(const int* __restrict__ ei, int E, int* __restrict__ degc) {
    int e = blockIdx.x * blockDim.x + threadIdx.x;
    if (e < E) atomicAdd(&degc[ei[E + e]], 1);
}

// ---- block-level exclusive scan ----
__global__ void k_scan_partial(const int* __restrict__ cnt, int n,
                               int* __restrict__ ex, int* __restrict__ bsum) {
    __shared__ int s[SCAN_B];
    int tid = threadIdx.x;
    int i = blockIdx.x * SCAN_B + tid;
    int v = (i < n) ? cnt[i] : 0;
    s[tid] = v;
    __syncthreads();
    for (int off = 1; off < SCAN_B; off <<= 1) {
        int t = (tid >= off) ? s[tid - off] : 0;
        __syncthreads();
        s[tid] += t;
        __syncthreads();
    }
    if (i < n) ex[i] = s[tid] - v;
    if (tid == SCAN_B - 1) bsum[blockIdx.x] = s[tid];
}

__global__ void k_scan_bsum(int* __restrict__ bsum, int nb) {
    __shared__ int s[SCAN_B];
    int tid = threadIdx.x;
    if (nb <= SCAN_B) {
        int v = (tid < nb) ? bsum[tid] : 0;
        s[tid] = v;
        __syncthreads();
        for (int off = 1; off < SCAN_B; off <<= 1) {
            int t = (tid >= off) ? s[tid - off] : 0;
            __syncthreads();
            s[tid] += t;
            __syncthreads();
        }
        if (tid < nb) bsum[tid] = s[tid] - v;
    } else {
        if (tid == 0) {
            int run = 0;
            for (int i = 0; i < nb; i++) { int t = bsum[i]; bsum[i] = run; run += t; }
        }
    }
}

__global__ void k_scan_add(int* __restrict__ rowptr, const int* __restrict__ boff,
                           const int* __restrict__ degc, int n, int E,
                           int* __restrict__ cursor, float* __restrict__ dinv) {
    int i = blockIdx.x * SCAN_B + threadIdx.x;
    if (i < n) {
        int v = rowptr[i] + boff[blockIdx.x];
        rowptr[i] = v;
        cursor[i] = v;
        dinv[i] = rsqrtf((float)(degc[i] + 1));  // +1 self-loop
    }
    if (i == 0) rowptr[n] = E;
}

__global__ void k_fill(const int* __restrict__ ei, int E,
                       int* __restrict__ cursor, int* __restrict__ col) {
    int e = blockIdx.x * blockDim.x + threadIdx.x;
    if (e < E) {
        int s = ei[e];
        int d = ei[E + e];
        int p = atomicAdd(&cursor[d], 1);
        col[p] = s;
    }
}

// ---- layer-1 dense: y[v][f] = dinv[v] * sum_k x[v][k] * W1[k][f] ----
__global__ void k_l1(const u16* __restrict__ x, const u16* __restrict__ wseg,
                     const float* __restrict__ dinv, int N, u16* __restrict__ y) {
    __shared__ float w[MOLD * HID];
    int tid = threadIdx.x;
    for (int i = tid; i < MOLD * HID; i += blockDim.x) w[i] = bf2f(wseg[i]);
    __syncthreads();
    int v = blockIdx.x * 4 + (tid >> 6);
    int f = tid & 63;
    if (v >= N) return;
    float acc = 0.f;
#pragma unroll
    for (int k = 0; k < MOLD; k++) acc += bf2f(x[v * MOLD + k]) * w[k * HID + f];
    y[v * HID + f] = f2bf(dinv[v] * acc);
}

// ---- CSR agg: h[v] = relu(dinv[v]*(y[v] + sum_nb y[u]) + b), wave per node ----
__global__ void k_agg(const u16* __restrict__ y, const int* __restrict__ rowptr,
                      const int* __restrict__ col, const float* __restrict__ dinv,
                      const u16* __restrict__ bseg, int N, u16* __restrict__ h) {
    int tid = threadIdx.x;
    int v = blockIdx.x * 4 + (tid >> 6);
    int f = tid & 63;
    if (v >= N) return;
    float acc = bf2f(y[v * HID + f]);  // self-loop (already dinv[src]-scaled)
    int s = rowptr[v], e = rowptr[v + 1];
    for (int i = s; i < e; i++) {
        int u = col[i];
        acc += bf2f(y[u * HID + f]);
    }
    float val = dinv[v] * acc + bf2f(bseg[f]);
    h[v * HID + f] = f2bf(fmaxf(val, 0.f));
}

// ---- dense 64x64: y[v][f] = dinv[v] * sum_k h[v][k]*W[k][f] ----
__global__ void k_mm64(const u16* __restrict__ h, const u16* __restrict__ wseg,
                       const float* __restrict__ dinv, int N, u16* __restrict__ y) {
    __shared__ float w[HID * HID];
    __shared__ float hl[4][HID];
    int tid = threadIdx.x;
    for (int i = tid; i < HID * HID; i += blockDim.x) w[i] = bf2f(wseg[i]);
    __syncthreads();
    int lane = tid & 63, nl = tid >> 6;
    int ngroups = (N + 3) / 4;
    for (int g = blockIdx.x; g < ngroups; g += gridDim.x) {
        int v = g * 4 + nl;
        __syncthreads();
        if (v < N) hl[nl][lane] = bf2f(h[v * HID + lane]);
        __syncthreads();
        if (v < N) {
            float acc = 0.f;
#pragma unroll 16
            for (int k = 0; k < HID; k++) acc += hl[nl][k] * w[k * HID + lane];
            y[v * HID + lane] = f2bf(dinv[v] * acc);
        }
    }
}

// ---- pooling (h >= 0 post-relu, so int atomicMax is order-preserving) ----
__global__ void k_pool(const u16* __restrict__ h, const int* __restrict__ batch, int N,
                       float* __restrict__ hsum, int* __restrict__ hmax, int* __restrict__ cnt) {
    int tid = threadIdx.x;
    int v = blockIdx.x * 4 + (tid >> 6);
    int f = tid & 63;
    if (v >= N) return;
    int g = batch[v];
    float val = bf2f(h[v * HID + f]);
    atomicAdd(&hsum[g * HID + f], val);
    atomicMax(&hmax[g * HID + f], __float_as_int(val));
    if (f == 0) atomicAdd(&cnt[g], 1);
}

// ---- final linear: out[g][f] = bl[f] + [mean|max] @ Wl ----
__global__ void k_final(const float* __restrict__ hsum, const int* __restrict__ hmaxi,
                        const int* __restrict__ cnt, const u16* __restrict__ wlseg,
                        const u16* __restrict__ blseg, const int* __restrict__ flag,
                        int G, void* __restrict__ out) {
    __shared__ float w[2 * HID * HID];  // 32 KB
    int tid = threadIdx.x;
    for (int i = tid; i < 2 * HID * HID; i += blockDim.x) w[i] = bf2f(wlseg[i]);
    __syncthreads();
    int g = blockIdx.x * 4 + (tid >> 6);
    int f = tid & 63;
    if (g >= G) return;
    float inv = 1.f / fmaxf((float)cnt[g], 1.f);
    float acc = bf2f(blseg[f]);
#pragma unroll 8
    for (int k = 0; k < HID; k++) acc += (hsum[g * HID + k] * inv) * w[k * HID + f];
#pragma unroll 8
    for (int k = 0; k < HID; k++) acc += __int_as_float(hmaxi[g * HID + k]) * w[(HID + k) * HID + f];
    int mode = *flag;
    if (mode) ((float*)out)[g * HID + f] = acc;
    else      ((u16*)out)[g * HID + f] = f2bf(acc);
}

extern "C" void kernel_launch(void* const* d_in, const int* in_sizes, int n_in,
                              void* d_out, int out_size, void* d_ws, size_t ws_size,
                              hipStream_t stream) {
    const void* x  = d_in[0];
    const int*  ei = (const int*)d_in[1];
    const int*  batch = (const int*)d_in[3];

    const int NX = in_sizes[0];        // N * 9 elements
    const int N  = NX / MOLD;
    const int E  = in_sizes[1] / 2;
    const int G  = out_size / HID;

    // ---- workspace carve-up (~68 MB) ----
    char* p = (char*)d_ws;
    auto alloc = [&](size_t bytes) -> char* {
        char* r = p;
        p += (bytes + 255) & ~(size_t)255;
        return r;
    };
    int*   flag   = (int*)alloc(256);
    int*   degc   = (int*)alloc((size_t)N * 4);
    int*   rowptr = (int*)alloc((size_t)(N + 1) * 4);
    int*   cursor = (int*)alloc((size_t)N * 4);
    float* dinv   = (float*)alloc((size_t)N * 4);
    int nb = (N + SCAN_B - 1) / SCAN_B;
    int*   bsum   = (int*)alloc((size_t)nb * 4);
    u16*   wbf    = (u16*)alloc((size_t)17216 * 2);
    // colb (E ints) aliases xbf (NX u16) — xbf dead before k_fill writes colb
    size_t uni = (size_t)E * 4;
    size_t xb  = (size_t)NX * 2;
    char*  ubase = alloc(uni > xb ? uni : xb);
    int*   colb = (int*)ubase;
    u16*   xbf  = (u16*)ubase;
    u16*   ybf  = (u16*)alloc((size_t)N * HID * 2);
    u16*   hbf  = (u16*)alloc((size_t)N * HID * 2);
    float* hsum = (float*)alloc((size_t)G * HID * 4);
    int*   hmax = (int*)alloc((size_t)G * HID * 4);
    int*   cnt  = (int*)alloc((size_t)G * 4);

    hipMemsetAsync(flag, 0, 256, stream);
    hipMemsetAsync(degc, 0, (size_t)N * 4, stream);
    hipMemsetAsync(hsum, 0, (size_t)G * HID * 4, stream);
    hipMemsetAsync(hmax, 0, (size_t)G * HID * 4, stream);  // 0 bits == 0.0f
    hipMemsetAsync(cnt, 0, (size_t)G * 4, stream);

    const int TPB = 256;
    int egrid = (E + TPB - 1) / TPB;
    int ngb = (N + 3) / 4;

    k_detect<<<1, 256, 0, stream>>>((const u16*)x, 8192, flag);
    k_cvt_w<<<1, 256, 0, stream>>>(d_in[4], d_in[5], d_in[6], d_in[7],
                                   d_in[8], d_in[9], d_in[10], d_in[11], flag, wbf);

    k_count<<<egrid, TPB, 0, stream>>>(ei, E, degc);
    k_scan_partial<<<nb, SCAN_B, 0, stream>>>(degc, N, rowptr, bsum);
    k_scan_bsum<<<1, SCAN_B, 0, stream>>>(bsum, nb);
    k_scan_add<<<nb, SCAN_B, 0, stream>>>(rowptr, bsum, degc, N, E, cursor, dinv);

    // stage x, run layer-1 dense BEFORE k_fill clobbers xbf with colb
    k_cvt_x<<<(NX + 255) / 256, 256, 0, stream>>>(x, xbf, NX, flag);
    k_l1<<<ngb, 256, 0, stream>>>(xbf, wbf + 0, dinv, N, ybf);
    k_fill<<<egrid, TPB, 0, stream>>>(ei, E, cursor, colb);

    k_agg<<<ngb, 256, 0, stream>>>(ybf, rowptr, colb, dinv, wbf + 576, N, hbf);
    k_mm64<<<1024, 256, 0, stream>>>(hbf, wbf + 640, dinv, N, ybf);
    k_agg<<<ngb, 256, 0, stream>>>(ybf, rowptr, colb, dinv, wbf + 4736, N, hbf);
    k_mm64<<<1024, 256, 0, stream>>>(hbf, wbf + 4800, dinv, N, ybf);
    k_agg<<<ngb, 256, 0, stream>>>(ybf, rowptr, colb, dinv, wbf + 8896, N, hbf);

    k_pool<<<ngb, 256, 0, stream>>>(hbf, batch, N, hsum, hmax, cnt);
    k_final<<<(G + 3) / 4, 256, 0, stream>>>(hsum, hmax, cnt, wbf + 8960, wbf + 17152,
                                             flag, G, d_out);
}

// Round 3
// 896.141 us; speedup vs baseline: 2.0576x; 2.0576x over previous
//
#include <hip/hip_runtime.h>

typedef unsigned short u16;
typedef __attribute__((ext_vector_type(8))) short short8;
typedef __attribute__((ext_vector_type(4))) float float4v;

#define HID 64
#define MOLD 9
#define SCAN_B 512

__device__ __forceinline__ float bf2f(u16 u) {
    return __uint_as_float(((unsigned)u) << 16);
}
__device__ __forceinline__ u16 f2bf(float f) {
    unsigned x = __float_as_uint(f);
    unsigned r = (x + 0x7FFFu + ((x >> 16) & 1u)) >> 16;  // round-nearest-even
    return (u16)r;
}
// unpack 8 bf16 (as uint4) and add into a[8]
__device__ __forceinline__ void unpack_add(uint4 r, float* a) {
    a[0] += __uint_as_float(r.x << 16); a[1] += __uint_as_float(r.x & 0xffff0000u);
    a[2] += __uint_as_float(r.y << 16); a[3] += __uint_as_float(r.y & 0xffff0000u);
    a[4] += __uint_as_float(r.z << 16); a[5] += __uint_as_float(r.z & 0xffff0000u);
    a[6] += __uint_as_float(r.w << 16); a[7] += __uint_as_float(r.w & 0xffff0000u);
}
__device__ __forceinline__ void unpack_set(uint4 r, float* a) {
    a[0] = __uint_as_float(r.x << 16); a[1] = __uint_as_float(r.x & 0xffff0000u);
    a[2] = __uint_as_float(r.y << 16); a[3] = __uint_as_float(r.y & 0xffff0000u);
    a[4] = __uint_as_float(r.z << 16); a[5] = __uint_as_float(r.z & 0xffff0000u);
    a[6] = __uint_as_float(r.w << 16); a[7] = __uint_as_float(r.w & 0xffff0000u);
}

// ---- dtype probe ----
__global__ void k_detect(const u16* __restrict__ p, int n, int* __restrict__ flag) {
    bool bad = false;
    for (int i = threadIdx.x; i < n; i += 256) {
        float v = bf2f(p[i]);
        if (!(v == v) || fabsf(v) > 1000.f) bad = true;
    }
    if (bad) atomicOr(flag, 1);
}

__device__ __forceinline__ void cvt_seg(const void* src, u16* dst, int n, int mode) {
    if (mode) {
        const float* s = (const float*)src;
        for (int i = threadIdx.x; i < n; i += 256) dst[i] = f2bf(s[i]);
    } else {
        const u16* s = (const u16*)src;
        for (int i = threadIdx.x; i < n; i += 256) dst[i] = s[i];
    }
}

__global__ void k_cvt_w(const void* W1, const void* b1, const void* W2, const void* b2,
                        const void* W3, const void* b3, const void* Wl, const void* bl,
                        const int* __restrict__ flag, u16* __restrict__ wbf) {
    int mode = *flag;
    cvt_seg(W1, wbf + 0,     MOLD * HID, mode);
    cvt_seg(b1, wbf + 576,   HID, mode);
    cvt_seg(W2, wbf + 640,   HID * HID, mode);
    cvt_seg(b2, wbf + 4736,  HID, mode);
    cvt_seg(W3, wbf + 4800,  HID * HID, mode);
    cvt_seg(b3, wbf + 8896,  HID, mode);
    cvt_seg(Wl, wbf + 8960,  2 * HID * HID, mode);
    cvt_seg(bl, wbf + 17152, HID, mode);
}

__global__ void k_cvt_x(const void* __restrict__ src, u16* __restrict__ dst, int n,
                        const int* __restrict__ flag) {
    int mode = *flag;
    int i = blockIdx.x * 256 + threadIdx.x;
    if (i >= n) return;
    dst[i] = mode ? f2bf(((const float*)src)[i]) : ((const u16*)src)[i];
}

// ---- CSR build ----
__global__ void k_count(const int* __restrict__ ei, int E, int* __restrict__ degc) {
    int e = blockIdx.x * blockDim.x + threadIdx.x;
    if (e < E) atomicAdd(&degc[ei[E + e]], 1);
}

__global__ void k_scan_partial(const int* __restrict__ cnt, int n,
                               int* __restrict__ ex, int* __restrict__ bsum) {
    __shared__ int s[SCAN_B];
    int tid = threadIdx.x;
    int i = blockIdx.x * SCAN_B + tid;
    int v = (i < n) ? cnt[i] : 0;
    s[tid] = v;
    __syncthreads();
    for (int off = 1; off < SCAN_B; off <<= 1) {
        int t = (tid >= off) ? s[tid - off] : 0;
        __syncthreads();
        s[tid] += t;
        __syncthreads();
    }
    if (i < n) ex[i] = s[tid] - v;
    if (tid == SCAN_B - 1) bsum[blockIdx.x] = s[tid];
}

__global__ void k_scan_bsum(int* __restrict__ bsum, int nb) {
    __shared__ int s[SCAN_B];
    int tid = threadIdx.x;
    if (nb <= SCAN_B) {
        int v = (tid < nb) ? bsum[tid] : 0;
        s[tid] = v;
        __syncthreads();
        for (int off = 1; off < SCAN_B; off <<= 1) {
            int t = (tid >= off) ? s[tid - off] : 0;
            __syncthreads();
            s[tid] += t;
            __syncthreads();
        }
        if (tid < nb) bsum[tid] = s[tid] - v;
    } else {
        if (tid == 0) {
            int run = 0;
            for (int i = 0; i < nb; i++) { int t = bsum[i]; bsum[i] = run; run += t; }
        }
    }
}

__global__ void k_scan_add(int* __restrict__ rowptr, const int* __restrict__ boff,
                           const int* __restrict__ degc, int n, int E,
                           int* __restrict__ cursor, float* __restrict__ dinv) {
    int i = blockIdx.x * SCAN_B + threadIdx.x;
    if (i < n) {
        int v = rowptr[i] + boff[blockIdx.x];
        rowptr[i] = v;
        cursor[i] = v;
        dinv[i] = rsqrtf((float)(degc[i] + 1));
    }
    if (i == 0) rowptr[n] = E;
}

__global__ void k_fill(const int* __restrict__ ei, int E,
                       int* __restrict__ cursor, int* __restrict__ col) {
    int e = blockIdx.x * blockDim.x + threadIdx.x;
    if (e < E) {
        int s = ei[e];
        int d = ei[E + e];
        int p = atomicAdd(&cursor[d], 1);
        col[p] = s;
    }
}

// ---- layer-1 dense ----
__global__ void k_l1(const u16* __restrict__ x, const u16* __restrict__ wseg,
                     const float* __restrict__ dinv, int N, u16* __restrict__ y) {
    __shared__ float w[MOLD * HID];
    int tid = threadIdx.x;
    for (int i = tid; i < MOLD * HID; i += blockDim.x) w[i] = bf2f(wseg[i]);
    __syncthreads();
    int v = blockIdx.x * 4 + (tid >> 6);
    int f = tid & 63;
    if (v >= N) return;
    float acc = 0.f;
#pragma unroll
    for (int k = 0; k < MOLD; k++) acc += bf2f(x[v * MOLD + k]) * w[k * HID + f];
    y[v * HID + f] = f2bf(dinv[v] * acc);
}

// ---- gather core: returns h[8] (post-relu) for feats fg*8+j, valid on ALL lanes ----
__device__ __forceinline__ void gather_node(const u16* __restrict__ y,
                                            const int* __restrict__ rowptr,
                                            const int* __restrict__ col,
                                            float dv, const float* breg,
                                            int v, int eslot, int fg, float* hj) {
    float acc[8];
    if (eslot == 0) {
        uint4 r = ((const uint4*)(y + (size_t)v * HID))[fg];
        unpack_set(r, acc);
    } else {
#pragma unroll
        for (int j = 0; j < 8; j++) acc[j] = 0.f;
    }
    int s = rowptr[v], e = rowptr[v + 1];
    for (int i = s; i < e; i += 8) {
        int idx = i + eslot;
        if (idx < e) {
            int u = col[idx];
            uint4 r = ((const uint4*)(y + (size_t)u * HID))[fg];
            unpack_add(r, acc);
        }
    }
    // butterfly over eslot (lane bits 3,4,5)
#pragma unroll
    for (int j = 0; j < 8; j++) acc[j] += __shfl_xor(acc[j], 8);
#pragma unroll
    for (int j = 0; j < 8; j++) acc[j] += __shfl_xor(acc[j], 16);
#pragma unroll
    for (int j = 0; j < 8; j++) acc[j] += __shfl_xor(acc[j], 32);
#pragma unroll
    for (int j = 0; j < 8; j++) hj[j] = fmaxf(dv * acc[j] + breg[j], 0.f);
}

__device__ __forceinline__ void load_bias(const u16* bseg, int fg, float* breg) {
    uint4 bv = ((const uint4*)bseg)[fg];
    unpack_set(bv, breg);
}

// ---- agg layers 1,2: h[v] = relu(dinv*(y[v]+sum y[u]) + b), wave per node (chunked) ----
__global__ __launch_bounds__(256, 4) void k_agg(
        const u16* __restrict__ y, const int* __restrict__ rowptr,
        const int* __restrict__ col, const float* __restrict__ dinv,
        const u16* __restrict__ bseg, int N, u16* __restrict__ h) {
    int lane = threadIdx.x & 63;
    int eslot = lane >> 3, fg = lane & 7;
    int wid = (blockIdx.x * blockDim.x + threadIdx.x) >> 6;
    int nw = (gridDim.x * blockDim.x) >> 6;
    float breg[8];
    load_bias(bseg, fg, breg);
    int cpw = (N + nw - 1) / nw;
    int v0 = wid * cpw;
    int v1 = v0 + cpw; if (v1 > N) v1 = N;
    for (int v = v0; v < v1; ++v) {
        float hj[8];
        gather_node(y, rowptr, col, dinv[v], breg, v, eslot, fg, hj);
        if (eslot == 0) {
            uint4 o;
            o.x = (unsigned)f2bf(hj[0]) | ((unsigned)f2bf(hj[1]) << 16);
            o.y = (unsigned)f2bf(hj[2]) | ((unsigned)f2bf(hj[3]) << 16);
            o.z = (unsigned)f2bf(hj[4]) | ((unsigned)f2bf(hj[5]) << 16);
            o.w = (unsigned)f2bf(hj[6]) | ((unsigned)f2bf(hj[7]) << 16);
            ((uint4*)(h + (size_t)v * HID))[fg] = o;
        }
    }
}

// ---- agg layer 3 + fused mean/max pooling (batch sorted -> run-flush) ----
__global__ __launch_bounds__(256, 4) void k_aggpool(
        const u16* __restrict__ y, const int* __restrict__ rowptr,
        const int* __restrict__ col, const float* __restrict__ dinv,
        const u16* __restrict__ bseg, const int* __restrict__ batch, int N,
        float* __restrict__ hsum, int* __restrict__ hmax, int* __restrict__ cnt) {
    int lane = threadIdx.x & 63;
    int eslot = lane >> 3, fg = lane & 7;
    int wid = (blockIdx.x * blockDim.x + threadIdx.x) >> 6;
    int nw = (gridDim.x * blockDim.x) >> 6;
    float breg[8];
    load_bias(bseg, fg, breg);
    int cpw = (N + nw - 1) / nw;
    int v0 = wid * cpw;
    int v1 = v0 + cpw; if (v1 > N) v1 = N;
    int gcur = -1, pcnt = 0;
    float psum[8], pmax[8];
#pragma unroll
    for (int j = 0; j < 8; j++) { psum[j] = 0.f; pmax[j] = 0.f; }
    for (int v = v0; v < v1; ++v) {
        float hj[8];
        gather_node(y, rowptr, col, dinv[v], breg, v, eslot, fg, hj);
        int g = batch[v];
        if (g != gcur) {
            if (gcur >= 0) {
                if (eslot == 0) {
#pragma unroll
                    for (int j = 0; j < 8; j++) {
                        atomicAdd(&hsum[gcur * HID + fg * 8 + j], psum[j]);
                        atomicMax(&hmax[gcur * HID + fg * 8 + j], __float_as_int(pmax[j]));
                    }
                }
                if (lane == 0) atomicAdd(&cnt[gcur], pcnt);
            }
#pragma unroll
            for (int j = 0; j < 8; j++) { psum[j] = 0.f; pmax[j] = 0.f; }
            pcnt = 0;
            gcur = g;
        }
        pcnt++;
#pragma unroll
        for (int j = 0; j < 8; j++) {
            psum[j] += hj[j];
            pmax[j] = fmaxf(pmax[j], hj[j]);
        }
    }
    if (gcur >= 0) {
        if (eslot == 0) {
#pragma unroll
            for (int j = 0; j < 8; j++) {
                atomicAdd(&hsum[gcur * HID + fg * 8 + j], psum[j]);
                atomicMax(&hmax[gcur * HID + fg * 8 + j], __float_as_int(pmax[j]));
            }
        }
        if (lane == 0) atomicAdd(&cnt[gcur], pcnt);
    }
}

// ---- MFMA 64x64 dense: y[v][f] = dinv[v] * sum_k h[v][k]*W[k][f] ----
// 16x16x32 bf16; A[m=lane&15][k=(lane>>4)*8+j]; D: row=(lane>>4)*4+r, col=lane&15
__global__ __launch_bounds__(256, 4) void k_mm(
        const u16* __restrict__ h, const u16* __restrict__ W,
        const float* __restrict__ dinv, int N, u16* __restrict__ y) {
    int lane = threadIdx.x & 63;
    int q = lane >> 4, m = lane & 15;
    int wid = (blockIdx.x * blockDim.x + threadIdx.x) >> 6;
    int nw = (gridDim.x * blockDim.x) >> 6;
    // B fragments: bfrag[tile][khalf][j] = W[kh*32 + q*8 + j][tile*16 + m]
    short8 bfrag[4][2];
#pragma unroll
    for (int t = 0; t < 4; ++t)
#pragma unroll
        for (int kh = 0; kh < 2; ++kh) {
            short8 bv;
#pragma unroll
            for (int j = 0; j < 8; ++j)
                bv[j] = (short)W[(kh * 32 + q * 8 + j) * HID + t * 16 + m];
            bfrag[t][kh] = bv;
        }
    const float4v zero = {0.f, 0.f, 0.f, 0.f};
    int ntiles = (N + 15) >> 4;
    for (int tile = wid; tile < ntiles; tile += nw) {
        int base = tile * 16;
        int row = base + m;
        short8 a0 = {0, 0, 0, 0, 0, 0, 0, 0}, a1 = a0;
        if (row < N) {
            uint4 r0 = *(const uint4*)(h + (size_t)row * HID + q * 8);
            uint4 r1 = *(const uint4*)(h + (size_t)row * HID + 32 + q * 8);
            a0 = __builtin_bit_cast(short8, r0);
            a1 = __builtin_bit_cast(short8, r1);
        }
        float4v c[4];
#pragma unroll
        for (int t = 0; t < 4; ++t) c[t] = zero;
#pragma unroll
        for (int t = 0; t < 4; ++t) {
            c[t] = __builtin_amdgcn_mfma_f32_16x16x32_bf16(a0, bfrag[t][0], c[t], 0, 0, 0);
            c[t] = __builtin_amdgcn_mfma_f32_16x16x32_bf16(a1, bfrag[t][1], c[t], 0, 0, 0);
        }
#pragma unroll
        for (int r = 0; r < 4; ++r) {
            int node = base + q * 4 + r;
            if (node < N) {
                float dv = dinv[node];
#pragma unroll
                for (int t = 0; t < 4; ++t)
                    y[(size_t)node * HID + t * 16 + m] = f2bf(c[t][r] * dv);
            }
        }
    }
}

// ---- final linear ----
__global__ void k_final(const float* __restrict__ hsum, const int* __restrict__ hmaxi,
                        const int* __restrict__ cnt, const u16* __restrict__ wlseg,
                        const u16* __restrict__ blseg, const int* __restrict__ flag,
                        int G, void* __restrict__ out) {
    __shared__ float w[2 * HID * HID];
    int tid = threadIdx.x;
    for (int i = tid; i < 2 * HID * HID; i += blockDim.x) w[i] = bf2f(wlseg[i]);
    __syncthreads();
    int g = blockIdx.x * 4 + (tid >> 6);
    int f = tid & 63;
    if (g >= G) return;
    float inv = 1.f / fmaxf((float)cnt[g], 1.f);
    float acc = bf2f(blseg[f]);
#pragma unroll 8
    for (int k = 0; k < HID; k++) acc += (hsum[g * HID + k] * inv) * w[k * HID + f];
#pragma unroll 8
    for (int k = 0; k < HID; k++) acc += __int_as_float(hmaxi[g * HID + k]) * w[(HID + k) * HID + f];
    int mode = *flag;
    if (mode) ((float*)out)[g * HID + f] = acc;
    else      ((u16*)out)[g * HID + f] = f2bf(acc);
}

extern "C" void kernel_launch(void* const* d_in, const int* in_sizes, int n_in,
                              void* d_out, int out_size, void* d_ws, size_t ws_size,
                              hipStream_t stream) {
    const void* x  = d_in[0];
    const int*  ei = (const int*)d_in[1];
    const int*  batch = (const int*)d_in[3];

    const int NX = in_sizes[0];
    const int N  = NX / MOLD;
    const int E  = in_sizes[1] / 2;
    const int G  = out_size / HID;

    char* p = (char*)d_ws;
    auto alloc = [&](size_t bytes) -> char* {
        char* r = p;
        p += (bytes + 255) & ~(size_t)255;
        return r;
    };
    int*   flag   = (int*)alloc(256);
    int*   degc   = (int*)alloc((size_t)N * 4);
    int*   rowptr = (int*)alloc((size_t)(N + 1) * 4);
    int*   cursor = (int*)alloc((size_t)N * 4);
    float* dinv   = (float*)alloc((size_t)N * 4);
    int nb = (N + SCAN_B - 1) / SCAN_B;
    int*   bsum   = (int*)alloc((size_t)nb * 4);
    u16*   wbf    = (u16*)alloc((size_t)17216 * 2);
    // colb (E ints) aliases xbf (NX u16) — xbf dead before k_fill writes colb
    size_t uni = (size_t)E * 4;
    size_t xb  = (size_t)NX * 2;
    char*  ubase = alloc(uni > xb ? uni : xb);
    int*   colb = (int*)ubase;
    u16*   xbf  = (u16*)ubase;
    u16*   ybf  = (u16*)alloc((size_t)N * HID * 2);
    u16*   hbf  = (u16*)alloc((size_t)N * HID * 2);
    float* hsum = (float*)alloc((size_t)G * HID * 4);
    int*   hmax = (int*)alloc((size_t)G * HID * 4);
    int*   cnt  = (int*)alloc((size_t)G * 4);

    hipMemsetAsync(flag, 0, 256, stream);
    hipMemsetAsync(degc, 0, (size_t)N * 4, stream);
    hipMemsetAsync(hsum, 0, (size_t)G * HID * 4, stream);
    hipMemsetAsync(hmax, 0, (size_t)G * HID * 4, stream);
    hipMemsetAsync(cnt, 0, (size_t)G * 4, stream);

    const int TPB = 256;
    int egrid = (E + TPB - 1) / TPB;
    int ngb = (N + 3) / 4;

    k_detect<<<1, 256, 0, stream>>>((const u16*)x, 8192, flag);
    k_cvt_w<<<1, 256, 0, stream>>>(d_in[4], d_in[5], d_in[6], d_in[7],
                                   d_in[8], d_in[9], d_in[10], d_in[11], flag, wbf);

    k_count<<<egrid, TPB, 0, stream>>>(ei, E, degc);
    k_scan_partial<<<nb, SCAN_B, 0, stream>>>(degc, N, rowptr, bsum);
    k_scan_bsum<<<1, SCAN_B, 0, stream>>>(bsum, nb);
    k_scan_add<<<nb, SCAN_B, 0, stream>>>(rowptr, bsum, degc, N, E, cursor, dinv);

    k_cvt_x<<<(NX + 255) / 256, 256, 0, stream>>>(x, xbf, NX, flag);
    k_l1<<<ngb, 256, 0, stream>>>(xbf, wbf + 0, dinv, N, ybf);
    k_fill<<<egrid, TPB, 0, stream>>>(ei, E, cursor, colb);   // clobbers xbf (dead)

    k_agg<<<2048, 256, 0, stream>>>(ybf, rowptr, colb, dinv, wbf + 576, N, hbf);
    k_mm<<<1024, 256, 0, stream>>>(hbf, wbf + 640, dinv, N, ybf);
    k_agg<<<2048, 256, 0, stream>>>(ybf, rowptr, colb, dinv, wbf + 4736, N, hbf);
    k_mm<<<1024, 256, 0, stream>>>(hbf, wbf + 4800, dinv, N, ybf);
    k_aggpool<<<2048, 256, 0, stream>>>(ybf, rowptr, colb, dinv, wbf + 8896, batch, N,
                                        hsum, hmax, cnt);

    k_final<<<(G + 3) / 4, 256, 0, stream>>>(hsum, hmax, cnt, wbf + 8960, wbf + 17152,
                                             flag, G, d_out);
}